// Round 5
// baseline (141.391 us; speedup 1.0000x reference)
//
#include <hip/hip_runtime.h>
#include <hip/hip_bf16.h>
#include <math.h>

#define S_LEN 2048
#define H_DIM 1024
#define NHEAD 16
#define HD 64
#define NMEM 4
#define NCHUNK 32
#define CLEN 64
#define EPS_C 1e-6f

typedef __attribute__((ext_vector_type(8))) short bf16x8;
typedef __attribute__((ext_vector_type(4))) float f32x4;
typedef __attribute__((ext_vector_type(8))) unsigned short u16x8;
typedef __attribute__((ext_vector_type(4))) unsigned short u16x4;

__device__ __forceinline__ unsigned short f2bf(float f) {
    unsigned int u = __float_as_uint(f);
    u += 0x7FFFu + ((u >> 16) & 1u);   // round-to-nearest-even
    return (unsigned short)(u >> 16);
}
__device__ __forceinline__ float bf2f(unsigned short u) {
    return __uint_as_float((unsigned int)u << 16);
}

// swizzle for 64x64 bf16 tiles, 128B rows (G4: byte ^= (row&7)<<4)
#define SWZ(row, colbyte) ((row) * 128 + ((colbyte) ^ (((row) & 7) << 4)))

// ---------------------------------------------------------------------------
// prep: all f32->bf16 conversions + memories transpose, one launch.
// blocks [0,1024): hidden -> hb        [1024,1536): w_q -> wb[0:1M)
// [1536,2048): w_k -> wb[1M:2M)        [2048,2560): w_v -> wb[2M:3M)
// [2560,3072): w_o -> wob              [3072,3136): memories -> mbT (transposed)
// ---------------------------------------------------------------------------
__global__ __launch_bounds__(256) void prep_kernel(const float* __restrict__ hidden,
                                                   const float* __restrict__ w_q,
                                                   const float* __restrict__ w_k,
                                                   const float* __restrict__ w_v,
                                                   const float* __restrict__ w_o,
                                                   const float* __restrict__ memories,
                                                   unsigned short* __restrict__ hb,
                                                   unsigned short* __restrict__ wb,
                                                   unsigned short* __restrict__ wob,
                                                   unsigned short* __restrict__ mbT) {
    const int b = blockIdx.x;
    const int tid = threadIdx.x;
    __shared__ float t[64][65];
    if (b < 3072) {
        const float* src;
        unsigned short* dst;
        int base;
        if (b < 1024)      { src = hidden; dst = hb;            base = b; }
        else if (b < 1536) { src = w_q;    dst = wb;            base = b - 1024; }
        else if (b < 2048) { src = w_k;    dst = wb + 1048576;  base = b - 1536; }
        else if (b < 2560) { src = w_v;    dst = wb + 2097152;  base = b - 2048; }
        else               { src = w_o;    dst = wob;           base = b - 2560; }
        const int i = base * 2048 + tid * 8;
        float4 a = *(const float4*)(src + i);
        float4 c = *(const float4*)(src + i + 4);
        u16x8 o;
        o[0] = f2bf(a.x); o[1] = f2bf(a.y); o[2] = f2bf(a.z); o[3] = f2bf(a.w);
        o[4] = f2bf(c.x); o[5] = f2bf(c.y); o[6] = f2bf(c.z); o[7] = f2bf(c.w);
        *(u16x8*)(dst + i) = o;
    } else {
        const int mh = b - 3072;
        const float* src = memories + (size_t)mh * 4096;
#pragma unroll
        for (int j = 0; j < 4; ++j) {
            const int idx = j * 1024 + tid * 4;
            *(float4*)&t[idx >> 6][idx & 63] = *(const float4*)&src[idx];
        }
        __syncthreads();
        unsigned short* dst = mbT + (size_t)mh * 4096;
#pragma unroll
        for (int j = 0; j < 4; ++j) {
            const int idx = j * 1024 + tid * 4;
            const int e = idx >> 6, d = idx & 63;
            u16x4 o;
#pragma unroll
            for (int i = 0; i < 4; ++i) o[i] = f2bf(t[d + i][e]);
            *(u16x4*)&dst[idx] = o;
        }
    }
}

// ---------------------------------------------------------------------------
// MFMA bf16 GEMM (m97 structure): C[m,n] = sum_k A[m,k]*B[n,k]
// MODE 0: f32 out (no act). MODE 1: qkv fused, bf16 out, elu1 on seg 0/1.
// ---------------------------------------------------------------------------
template <int MODE>
__global__ __launch_bounds__(256) void gemm_mfma_kernel(const unsigned short* __restrict__ A,
                                                        const unsigned short* __restrict__ B,
                                                        float* __restrict__ f32out,
                                                        unsigned short* __restrict__ b0,
                                                        unsigned short* __restrict__ b1,
                                                        unsigned short* __restrict__ b2,
                                                        int K) {
    __shared__ unsigned short Als[128][32];
    __shared__ unsigned short Bls[128][32];
    const int tid  = threadIdx.x;
    const int lane = tid & 63;
    const int wv   = tid >> 6;
    const int wr   = wv >> 1;
    const int wc   = wv & 1;
    const int bm   = blockIdx.x * 128;
    const int bn   = blockIdx.y * 128;

    const int srow = (wv << 5) + (lane >> 2);
    const int skc  = (lane & 3) << 3;
    const unsigned short* gA = A + (size_t)(bm + srow) * K + skc;
    const unsigned short* gB = B + (size_t)(bn + srow) * K + skc;

    const int frow = lane & 15;
    const int fkof = (lane >> 4) << 3;

    f32x4 acc[4][4] = {};

    for (int k0 = 0; k0 < K; k0 += 32) {
        __syncthreads();
        __builtin_amdgcn_global_load_lds(
            (const __attribute__((address_space(1))) void*)(gA + k0),
            (__attribute__((address_space(3))) void*)&Als[(wv << 5)][0], 16, 0, 0);
        __builtin_amdgcn_global_load_lds(
            (const __attribute__((address_space(1))) void*)(gA + k0 + 16 * (size_t)K),
            (__attribute__((address_space(3))) void*)&Als[(wv << 5) + 16][0], 16, 0, 0);
        __builtin_amdgcn_global_load_lds(
            (const __attribute__((address_space(1))) void*)(gB + k0),
            (__attribute__((address_space(3))) void*)&Bls[(wv << 5)][0], 16, 0, 0);
        __builtin_amdgcn_global_load_lds(
            (const __attribute__((address_space(1))) void*)(gB + k0 + 16 * (size_t)K),
            (__attribute__((address_space(3))) void*)&Bls[(wv << 5) + 16][0], 16, 0, 0);
        __syncthreads();

        bf16x8 af[4], bf[4];
#pragma unroll
        for (int mi = 0; mi < 4; ++mi)
            af[mi] = *(const bf16x8*)&Als[wr * 64 + mi * 16 + frow][fkof];
#pragma unroll
        for (int ni = 0; ni < 4; ++ni)
            bf[ni] = *(const bf16x8*)&Bls[wc * 64 + ni * 16 + frow][fkof];
#pragma unroll
        for (int mi = 0; mi < 4; ++mi)
#pragma unroll
            for (int ni = 0; ni < 4; ++ni)
                acc[mi][ni] = __builtin_amdgcn_mfma_f32_16x16x32_bf16(af[mi], bf[ni], acc[mi][ni], 0, 0, 0);
    }

    unsigned short* bdst = b0;
    int colbase = bn;
    bool act = false;
    if (MODE == 1) {
        const int seg = bn >> 10;
        bdst = (seg == 0) ? b0 : ((seg == 1) ? b1 : b2);
        colbase = bn & 1023;
        act = (seg < 2);
    }
    const int crow = (lane >> 4) << 2;
    const int ccol = lane & 15;
#pragma unroll
    for (int mi = 0; mi < 4; ++mi) {
#pragma unroll
        for (int ni = 0; ni < 4; ++ni) {
            const int col = colbase + wc * 64 + ni * 16 + ccol;
#pragma unroll
            for (int r = 0; r < 4; ++r) {
                const int row = bm + wr * 64 + mi * 16 + crow + r;
                float x = acc[mi][ni][r];
                if (MODE == 0) {
                    f32out[(size_t)row * 1024 + col] = x;
                } else {
                    if (act) x = (x > 0.f) ? (x + 1.f) : __expf(x);
                    bdst[(size_t)row * 1024 + col] = f2bf(x);
                }
            }
        }
    }
}

// ---------------------------------------------------------------------------
// rel[m,h,s] = sum_d qb[s, h*64+d] * norms[m,h,d];  relsum[m,h] = sum_s rel
// ---------------------------------------------------------------------------
__global__ __launch_bounds__(256) void rel_kernel(const unsigned short* __restrict__ qb,
                                                  const float* __restrict__ norms,
                                                  float* __restrict__ rel,
                                                  float* __restrict__ relsum) {
    const int m = blockIdx.x >> 4;
    const int h = blockIdx.x & 15;
    __shared__ float nl[64];
    __shared__ float red[256];
    const int tid = threadIdx.x;
    if (tid < 64) nl[tid] = norms[(size_t)(m * NHEAD + h) * HD + tid];
    __syncthreads();
    float lsum = 0.f;
    for (int s = tid; s < S_LEN; s += 256) {
        const unsigned short* row = qb + (size_t)s * H_DIM + h * HD;
        float dot = 0.f;
#pragma unroll
        for (int d = 0; d < 64; d += 8) {
            u16x8 v = *(const u16x8*)(row + d);
#pragma unroll
            for (int i = 0; i < 8; ++i) dot += bf2f(v[i]) * nl[d + i];
        }
        rel[(size_t)(m * NHEAD + h) * S_LEN + s] = dot;
        lsum += dot;
    }
    red[tid] = lsum;
    __syncthreads();
    for (int o = 128; o > 0; o >>= 1) {
        if (tid < o) red[tid] += red[tid + o];
        __syncthreads();
    }
    if (tid == 0) relsum[m * NHEAD + h] = red[0];
}

// ---------------------------------------------------------------------------
// kvstate: per head, MFMA chunk-KV with fused exclusive prefix.
//   acc (MFMA C layout) IS the running prefix: per chunk write acc as bf16
//   (ckvT_b[h,c][e][d] = sum_{chunks<c} v[s,e]k[s,d]), then accumulate chunk.
//   cks[h,c,d] = exclusive prefix of per-chunk k-sums (f32).
// grid: NHEAD blocks, 256 threads (4 waves, wave w owns e-rows [16w,16w+16)).
// ---------------------------------------------------------------------------
__global__ __launch_bounds__(256) void kvstate_kernel(const unsigned short* __restrict__ kb,
                                                      const unsigned short* __restrict__ vb,
                                                      unsigned short* __restrict__ ckvT_b,
                                                      float* __restrict__ cks) {
    const int h = blockIdx.x;
    __shared__ unsigned short KT[4096], VT[4096];   // swizzled [d][s], [e][s]
    __shared__ float ksum_run[64];
    char* KTb = (char*)KT;
    char* VTb = (char*)VT;
    const int tid = threadIdx.x;
    const int lane = tid & 63;
    const int w = tid >> 6;
    const int fr = lane & 15;
    const int fk = (lane >> 4) * 8;
    const int er = w * 16 + (lane >> 4) * 4;      // epilogue e-row base

    const int idx0 = tid * 8, idx1 = 2048 + tid * 8;
    const int r0 = idx0 >> 6, c0 = idx0 & 63;
    const int r1 = idx1 >> 6, c1 = idx1 & 63;

    f32x4 acc[4] = {};
    if (tid < 64) ksum_run[tid] = 0.f;

    // prefetch chunk 0
    u16x8 pk0 = *(const u16x8*)&kb[(size_t)r0 * H_DIM + h * HD + c0];
    u16x8 pk1 = *(const u16x8*)&kb[(size_t)r1 * H_DIM + h * HD + c1];
    u16x8 pv0 = *(const u16x8*)&vb[(size_t)r0 * H_DIM + h * HD + c0];
    u16x8 pv1 = *(const u16x8*)&vb[(size_t)r1 * H_DIM + h * HD + c1];

    for (int c = 0; c < NCHUNK; ++c) {
        // 1. write exclusive-prefix outputs for chunk c
        unsigned short* dst = ckvT_b + ((size_t)(h * NCHUNK + c) << 12);
#pragma unroll
        for (int nt = 0; nt < 4; ++nt) {
            const int d = nt * 16 + fr;
#pragma unroll
            for (int r = 0; r < 4; ++r)
                dst[(er + r) * 64 + d] = f2bf(acc[nt][r]);
        }
        if (tid < 64) cks[(size_t)(h * NCHUNK + c) * HD + tid] = ksum_run[tid];
        __syncthreads();   // prev iter's LDS readers done

        // 2. stage chunk c from prefetch regs (transposed, swizzled)
#pragma unroll
        for (int j = 0; j < 8; ++j) {
            *(unsigned short*)(KTb + SWZ(c0 + j, r0 * 2)) = (unsigned short)pk0[j];
            *(unsigned short*)(KTb + SWZ(c1 + j, r1 * 2)) = (unsigned short)pk1[j];
            *(unsigned short*)(VTb + SWZ(c0 + j, r0 * 2)) = (unsigned short)pv0[j];
            *(unsigned short*)(VTb + SWZ(c1 + j, r1 * 2)) = (unsigned short)pv1[j];
        }
        // 3. prefetch chunk c+1 (hides under barrier + MFMA)
        if (c + 1 < NCHUNK) {
            const int sn = (c + 1) * CLEN;
            pk0 = *(const u16x8*)&kb[(size_t)(sn + r0) * H_DIM + h * HD + c0];
            pk1 = *(const u16x8*)&kb[(size_t)(sn + r1) * H_DIM + h * HD + c1];
            pv0 = *(const u16x8*)&vb[(size_t)(sn + r0) * H_DIM + h * HD + c0];
            pv1 = *(const u16x8*)&vb[(size_t)(sn + r1) * H_DIM + h * HD + c1];
        }
        __syncthreads();

        // 4. MFMA accumulate: acc[e-tile][d-tiles] += V^T K
        bf16x8 a0 = *(bf16x8*)(VTb + SWZ(w * 16 + fr, fk * 2));
        bf16x8 a1 = *(bf16x8*)(VTb + SWZ(w * 16 + fr, (32 + fk) * 2));
#pragma unroll
        for (int nt = 0; nt < 4; ++nt) {
            bf16x8 b0 = *(bf16x8*)(KTb + SWZ(nt * 16 + fr, fk * 2));
            bf16x8 b1 = *(bf16x8*)(KTb + SWZ(nt * 16 + fr, (32 + fk) * 2));
            acc[nt] = __builtin_amdgcn_mfma_f32_16x16x32_bf16(a0, b0, acc[nt], 0, 0, 0);
            acc[nt] = __builtin_amdgcn_mfma_f32_16x16x32_bf16(a1, b1, acc[nt], 0, 0, 0);
        }
        // 5. ksum update (lanes 0..63 of wave 0; same threads write cks next iter)
        if (tid < 64) {
            float s = 0.f;
#pragma unroll
            for (int si = 0; si < 64; ++si)
                s += bf2f(*(unsigned short*)(KTb + SWZ(tid, si * 2)));
            ksum_run[tid] += s;
        }
    }
}

// ---------------------------------------------------------------------------
// Fused output kernel for one (head, chunk): memory retrieval + causal local
// attention, all MFMA; softmax memory weights computed inline.
//   local[s,e] = (P@V + Q@KVpre)[s,e] / den[s]
//   mem[s,e]   = sum_m c[m,s] * (Q @ M_m^T)[s,e],  c = w_m/max(rel,eps)
//   cb[s,e]    = bf16( g*mem + (1-g)*local )
// ---------------------------------------------------------------------------
__global__ __launch_bounds__(256) void fused_out_kernel(const unsigned short* __restrict__ qb,
                                                        const unsigned short* __restrict__ kb,
                                                        const unsigned short* __restrict__ vb,
                                                        const unsigned short* __restrict__ ckvT_b,
                                                        const float* __restrict__ cks,
                                                        const unsigned short* __restrict__ mbT,
                                                        const float* __restrict__ rel,
                                                        const float* __restrict__ relsum,
                                                        const float* __restrict__ gate,
                                                        unsigned short* __restrict__ cb) {
    const int h = blockIdx.x;
    const int c = blockIdx.y;
    const int s0 = c * CLEN;
    __shared__ unsigned short Qs[4096], Ks[4096], VsT[4096], KVsT[4096], Ps[4096];
    __shared__ unsigned short Ms[4][4096];
    __shared__ float kp_lds[64];
    __shared__ float den_lds[64];
    __shared__ float c_lds[4][64];
    char* Qb  = (char*)Qs;
    char* Kb  = (char*)Ks;
    char* Vb  = (char*)VsT;
    char* KVb = (char*)KVsT;
    char* Pb  = (char*)Ps;
    const int tid = threadIdx.x;
    const int lane = tid & 63;
    const int w = tid >> 6;

    // --- stage Q, K (row-major), V (transposed) ---
#pragma unroll
    for (int p = 0; p < 2; ++p) {
        const int idx = p * 2048 + tid * 8;
        const int r = idx >> 6, cc = idx & 63;
        const size_t gidx = (size_t)(s0 + r) * H_DIM + h * HD + cc;
        u16x8 q8 = *(const u16x8*)&qb[gidx];
        u16x8 k8 = *(const u16x8*)&kb[gidx];
        u16x8 v8 = *(const u16x8*)&vb[gidx];
        *(u16x8*)(Qb + SWZ(r, cc * 2)) = q8;
        *(u16x8*)(Kb + SWZ(r, cc * 2)) = k8;
#pragma unroll
        for (int j = 0; j < 8; ++j)
            *(unsigned short*)(Vb + SWZ(cc + j, r * 2)) = (unsigned short)v8[j];
    }
    // --- stage KVpre^T (bf16, already [e][d]) + memories ---
    const unsigned short* kvsrc = ckvT_b + ((size_t)(h * NCHUNK + c) << 12);
#pragma unroll
    for (int p = 0; p < 2; ++p) {
        const int idx = p * 2048 + tid * 8;
        const int e = idx >> 6, d = idx & 63;
        *(u16x8*)(KVb + SWZ(e, d * 2)) = *(const u16x8*)&kvsrc[idx];
    }
#pragma unroll
    for (int m = 0; m < NMEM; ++m) {
        const unsigned short* msrc = mbT + (size_t)(m * NHEAD + h) * 4096;
        char* Mb = (char*)Ms[m];
#pragma unroll
        for (int p = 0; p < 2; ++p) {
            const int idx = p * 2048 + tid * 8;
            const int e = idx >> 6, d = idx & 63;
            *(u16x8*)(Mb + SWZ(e, d * 2)) = *(const u16x8*)&msrc[idx];
        }
    }
    if (tid < 64) kp_lds[tid] = cks[(size_t)(h * NCHUNK + c) * HD + tid];
    {
        // inline softmax weights over memories (redundant per thread, 4 loads)
        const int m = tid >> 6, si = tid & 63;
        float v[NMEM], mx = -1e30f;
#pragma unroll
        for (int mm = 0; mm < NMEM; ++mm) {
            v[mm] = relsum[mm * NHEAD + h] * (1.f / (float)S_LEN);
            mx = fmaxf(mx, v[mm]);
        }
        float sum = 0.f;
#pragma unroll
        for (int mm = 0; mm < NMEM; ++mm) { v[mm] = __expf(v[mm] - mx); sum += v[mm]; }
        const float wgt = v[m] / sum;
        c_lds[m][si] = wgt / fmaxf(rel[(size_t)(m * NHEAD + h) * S_LEN + s0 + si], EPS_C);
    }
    __syncthreads();

    // --- den_init[s] = q[s]·kpre ---
    {
        const int s = tid >> 2, part = tid & 3;
        float acc = 0.f;
#pragma unroll
        for (int j = 0; j < 16; ++j) {
            const int d = part * 16 + j;
            acc += bf2f(*(unsigned short*)(Qb + SWZ(s, d * 2))) * kp_lds[d];
        }
        acc += __shfl_xor(acc, 1);
        acc += __shfl_xor(acc, 2);
        if (part == 0) den_lds[s] = acc;
    }

    // --- QK^T ---
    const int sb = w * 16;
    const int fr = lane & 15;
    const int fk = (lane >> 4) * 8;
    bf16x8 aq0 = *(bf16x8*)(Qb + SWZ(sb + fr, fk * 2));
    bf16x8 aq1 = *(bf16x8*)(Qb + SWZ(sb + fr, (32 + fk) * 2));
    f32x4 aqk[4] = {};
#pragma unroll
    for (int nt = 0; nt < 4; ++nt) {
        bf16x8 bk0 = *(bf16x8*)(Kb + SWZ(nt * 16 + fr, fk * 2));
        bf16x8 bk1 = *(bf16x8*)(Kb + SWZ(nt * 16 + fr, (32 + fk) * 2));
        aqk[nt] = __builtin_amdgcn_mfma_f32_16x16x32_bf16(aq0, bk0, aqk[nt], 0, 0, 0);
        aqk[nt] = __builtin_amdgcn_mfma_f32_16x16x32_bf16(aq1, bk1, aqk[nt], 0, 0, 0);
    }
    // mask (t<=s), write P bf16, accumulate row sums
    float rs[4] = {0.f, 0.f, 0.f, 0.f};
    const int srow0 = sb + (lane >> 4) * 4;
#pragma unroll
    for (int nt = 0; nt < 4; ++nt) {
        const int t = nt * 16 + fr;
#pragma unroll
        for (int r = 0; r < 4; ++r) {
            const int s = srow0 + r;
            const float pv = (t <= s) ? aqk[nt][r] : 0.f;
            rs[r] += pv;
            *(unsigned short*)(Pb + SWZ(s, t * 2)) = f2bf(pv);
        }
    }
#pragma unroll
    for (int m = 1; m < 16; m <<= 1) {
        rs[0] += __shfl_xor(rs[0], m);
        rs[1] += __shfl_xor(rs[1], m);
        rs[2] += __shfl_xor(rs[2], m);
        rs[3] += __shfl_xor(rs[3], m);
    }
    if (fr == 0) {
#pragma unroll
        for (int r = 0; r < 4; ++r) den_lds[srow0 + r] += rs[r];
    }
    __syncthreads();

    // --- num = P@V + Q@KVpre; mem = sum_m c_m * (Q@M_m^T); epilogue ---
    const float g = 1.f / (1.f + __expf(-gate[h]));
    const float gl = 1.f - g;
#pragma unroll
    for (int nt = 0; nt < 4; ++nt) {
        const int br = nt * 16 + fr;
        f32x4 lacc = {};
        bf16x8 ap0 = *(bf16x8*)(Pb + SWZ(sb + fr, fk * 2));
        bf16x8 ap1 = *(bf16x8*)(Pb + SWZ(sb + fr, (32 + fk) * 2));
        bf16x8 bv0 = *(bf16x8*)(Vb + SWZ(br, fk * 2));
        bf16x8 bv1 = *(bf16x8*)(Vb + SWZ(br, (32 + fk) * 2));
        lacc = __builtin_amdgcn_mfma_f32_16x16x32_bf16(ap0, bv0, lacc, 0, 0, 0);
        lacc = __builtin_amdgcn_mfma_f32_16x16x32_bf16(ap1, bv1, lacc, 0, 0, 0);
        bf16x8 bkv0 = *(bf16x8*)(KVb + SWZ(br, fk * 2));
        bf16x8 bkv1 = *(bf16x8*)(KVb + SWZ(br, (32 + fk) * 2));
        lacc = __builtin_amdgcn_mfma_f32_16x16x32_bf16(aq0, bkv0, lacc, 0, 0, 0);
        lacc = __builtin_amdgcn_mfma_f32_16x16x32_bf16(aq1, bkv1, lacc, 0, 0, 0);

        f32x4 macc = {};
#pragma unroll
        for (int m = 0; m < NMEM; ++m) {
            char* Mb = (char*)Ms[m];
            bf16x8 bm0 = *(bf16x8*)(Mb + SWZ(br, fk * 2));
            bf16x8 bm1 = *(bf16x8*)(Mb + SWZ(br, (32 + fk) * 2));
            f32x4 mm = {};
            mm = __builtin_amdgcn_mfma_f32_16x16x32_bf16(aq0, bm0, mm, 0, 0, 0);
            mm = __builtin_amdgcn_mfma_f32_16x16x32_bf16(aq1, bm1, mm, 0, 0, 0);
#pragma unroll
            for (int r = 0; r < 4; ++r)
                macc[r] = fmaf(c_lds[m][srow0 + r], mm[r], macc[r]);
        }

        const int e = nt * 16 + fr;
#pragma unroll
        for (int r = 0; r < 4; ++r) {
            const int s = srow0 + r;
            const float den = fmaxf(den_lds[s], EPS_C);
            const float val = g * macc[r] + gl * lacc[r] / den;
            cb[(size_t)(s0 + s) * H_DIM + h * HD + e] = f2bf(val);
        }
    }
}

extern "C" void kernel_launch(void* const* d_in, const int* in_sizes, int n_in,
                              void* d_out, int out_size, void* d_ws, size_t ws_size,
                              hipStream_t stream) {
    const float* hidden   = (const float*)d_in[0];
    const float* w_q      = (const float*)d_in[1];
    const float* w_k      = (const float*)d_in[2];
    const float* w_v      = (const float*)d_in[3];
    const float* w_o      = (const float*)d_in[4];
    const float* gate     = (const float*)d_in[5];
    const float* memories = (const float*)d_in[6];
    const float* memnorms = (const float*)d_in[7];
    float* out = (float*)d_out;

    float* ws = (float*)d_ws;
    size_t off = 0;
    float* rel    = ws + off; off += (size_t)NMEM * NHEAD * S_LEN;
    float* relsum = ws + off; off += 64;
    float* cks    = ws + off; off += (size_t)NHEAD * NCHUNK * HD;
    unsigned short* ckvT_b = (unsigned short*)(ws + off); off += (size_t)NHEAD * NCHUNK * HD * HD / 2;
    unsigned short* hb  = (unsigned short*)(ws + off); off += (size_t)S_LEN * H_DIM / 2;
    unsigned short* wb  = (unsigned short*)(ws + off); off += (size_t)3 * H_DIM * H_DIM / 2;
    unsigned short* wob = (unsigned short*)(ws + off); off += (size_t)H_DIM * H_DIM / 2;
    unsigned short* qb  = (unsigned short*)(ws + off); off += (size_t)S_LEN * H_DIM / 2;
    unsigned short* kb  = (unsigned short*)(ws + off); off += (size_t)S_LEN * H_DIM / 2;
    unsigned short* vb  = (unsigned short*)(ws + off); off += (size_t)S_LEN * H_DIM / 2;
    unsigned short* cb  = (unsigned short*)(ws + off); off += (size_t)S_LEN * H_DIM / 2;
    unsigned short* mbT = (unsigned short*)(ws + off); off += (size_t)NMEM * NHEAD * HD * HD / 2;

    // 1. all conversions + memory transpose (one launch)
    prep_kernel<<<3136, 256, 0, stream>>>(hidden, w_q, w_k, w_v, w_o, memories,
                                          hb, wb, wob, mbT);
    // 2. fused QKV projection -> q/k/v bf16
    gemm_mfma_kernel<1><<<dim3(S_LEN / 128, 3 * H_DIM / 128), 256, 0, stream>>>(
        hb, wb, nullptr, qb, kb, vb, H_DIM);
    // 3. memory-selection relevance
    rel_kernel<<<NMEM * NHEAD, 256, 0, stream>>>(qb, memnorms, rel, relsum);
    // 4. chunk-KV state + exclusive prefix (MFMA, fused)
    kvstate_kernel<<<NHEAD, 256, 0, stream>>>(kb, vb, ckvT_b, cks);
    // 5. fused memory + local output
    fused_out_kernel<<<dim3(NHEAD, NCHUNK), 256, 0, stream>>>(
        qb, kb, vb, ckvT_b, cks, mbT, rel, relsum, gate, cb);
    // 6. output projection
    gemm_mfma_kernel<0><<<dim3(S_LEN / 128, H_DIM / 128), 256, 0, stream>>>(
        cb, wob, out, nullptr, nullptr, nullptr, H_DIM);
}

// Round 6
// 93.798 us; speedup vs baseline: 1.5074x; 1.5074x over previous
//
#include <hip/hip_runtime.h>
#include <hip/hip_bf16.h>
#include <math.h>

#define S_LEN 2048
#define H_DIM 1024
#define NHEAD 16
#define HD 64
#define NMEM 4
#define NCHUNK 32
#define CLEN 64
#define EPS_C 1e-6f

typedef __attribute__((ext_vector_type(8))) short bf16x8;
typedef __attribute__((ext_vector_type(4))) float f32x4;
typedef __attribute__((ext_vector_type(8))) unsigned short u16x8;
typedef __attribute__((ext_vector_type(4))) unsigned short u16x4;

__device__ __forceinline__ unsigned short f2bf(float f) {
    unsigned int u = __float_as_uint(f);
    u += 0x7FFFu + ((u >> 16) & 1u);   // round-to-nearest-even
    return (unsigned short)(u >> 16);
}
__device__ __forceinline__ float bf2f(unsigned short u) {
    return __uint_as_float((unsigned int)u << 16);
}

// swizzle for 64x64 bf16 tiles, 128B rows (G4: byte ^= (row&7)<<4)
#define SWZ(row, colbyte) ((row) * 128 + ((colbyte) ^ (((row) & 7) << 4)))

// ---------------------------------------------------------------------------
// prep: all f32->bf16 conversions + memories transpose, one launch.
// ---------------------------------------------------------------------------
__global__ __launch_bounds__(256) void prep_kernel(const float* __restrict__ hidden,
                                                   const float* __restrict__ w_q,
                                                   const float* __restrict__ w_k,
                                                   const float* __restrict__ w_v,
                                                   const float* __restrict__ w_o,
                                                   const float* __restrict__ memories,
                                                   unsigned short* __restrict__ hb,
                                                   unsigned short* __restrict__ wb,
                                                   unsigned short* __restrict__ wob,
                                                   unsigned short* __restrict__ mbT) {
    const int b = blockIdx.x;
    const int tid = threadIdx.x;
    __shared__ float t[64][65];
    if (b < 3072) {
        const float* src;
        unsigned short* dst;
        int base;
        if (b < 1024)      { src = hidden; dst = hb;            base = b; }
        else if (b < 1536) { src = w_q;    dst = wb;            base = b - 1024; }
        else if (b < 2048) { src = w_k;    dst = wb + 1048576;  base = b - 1536; }
        else if (b < 2560) { src = w_v;    dst = wb + 2097152;  base = b - 2048; }
        else               { src = w_o;    dst = wob;           base = b - 2560; }
        const int i = base * 2048 + tid * 8;
        float4 a = *(const float4*)(src + i);
        float4 c = *(const float4*)(src + i + 4);
        u16x8 o;
        o[0] = f2bf(a.x); o[1] = f2bf(a.y); o[2] = f2bf(a.z); o[3] = f2bf(a.w);
        o[4] = f2bf(c.x); o[5] = f2bf(c.y); o[6] = f2bf(c.z); o[7] = f2bf(c.w);
        *(u16x8*)(dst + i) = o;
    } else {
        const int mh = b - 3072;
        const float* src = memories + (size_t)mh * 4096;
#pragma unroll
        for (int j = 0; j < 4; ++j) {
            const int idx = j * 1024 + tid * 4;
            *(float4*)&t[idx >> 6][idx & 63] = *(const float4*)&src[idx];
        }
        __syncthreads();
        unsigned short* dst = mbT + (size_t)mh * 4096;
#pragma unroll
        for (int j = 0; j < 4; ++j) {
            const int idx = j * 1024 + tid * 4;
            const int e = idx >> 6, d = idx & 63;
            u16x4 o;
#pragma unroll
            for (int i = 0; i < 4; ++i) o[i] = f2bf(t[d + i][e]);
            *(u16x4*)&dst[idx] = o;
        }
    }
}

// ---------------------------------------------------------------------------
// MFMA bf16 GEMM (m97 structure): C[m,n] = sum_k A[m,k]*B[n,k]
// MODE 0: f32 out (no act). MODE 1: qkv fused, bf16 out, elu1 on seg 0/1.
// ---------------------------------------------------------------------------
template <int MODE>
__global__ __launch_bounds__(256) void gemm_mfma_kernel(const unsigned short* __restrict__ A,
                                                        const unsigned short* __restrict__ B,
                                                        float* __restrict__ f32out,
                                                        unsigned short* __restrict__ b0,
                                                        unsigned short* __restrict__ b1,
                                                        unsigned short* __restrict__ b2,
                                                        int K) {
    __shared__ unsigned short Als[128][32];
    __shared__ unsigned short Bls[128][32];
    const int tid  = threadIdx.x;
    const int lane = tid & 63;
    const int wv   = tid >> 6;
    const int wr   = wv >> 1;
    const int wc   = wv & 1;
    const int bm   = blockIdx.x * 128;
    const int bn   = blockIdx.y * 128;

    const int srow = (wv << 5) + (lane >> 2);
    const int skc  = (lane & 3) << 3;
    const unsigned short* gA = A + (size_t)(bm + srow) * K + skc;
    const unsigned short* gB = B + (size_t)(bn + srow) * K + skc;

    const int frow = lane & 15;
    const int fkof = (lane >> 4) << 3;

    f32x4 acc[4][4] = {};

    for (int k0 = 0; k0 < K; k0 += 32) {
        __syncthreads();
        __builtin_amdgcn_global_load_lds(
            (const __attribute__((address_space(1))) void*)(gA + k0),
            (__attribute__((address_space(3))) void*)&Als[(wv << 5)][0], 16, 0, 0);
        __builtin_amdgcn_global_load_lds(
            (const __attribute__((address_space(1))) void*)(gA + k0 + 16 * (size_t)K),
            (__attribute__((address_space(3))) void*)&Als[(wv << 5) + 16][0], 16, 0, 0);
        __builtin_amdgcn_global_load_lds(
            (const __attribute__((address_space(1))) void*)(gB + k0),
            (__attribute__((address_space(3))) void*)&Bls[(wv << 5)][0], 16, 0, 0);
        __builtin_amdgcn_global_load_lds(
            (const __attribute__((address_space(1))) void*)(gB + k0 + 16 * (size_t)K),
            (__attribute__((address_space(3))) void*)&Bls[(wv << 5) + 16][0], 16, 0, 0);
        __syncthreads();

        bf16x8 af[4], bf[4];
#pragma unroll
        for (int mi = 0; mi < 4; ++mi)
            af[mi] = *(const bf16x8*)&Als[wr * 64 + mi * 16 + frow][fkof];
#pragma unroll
        for (int ni = 0; ni < 4; ++ni)
            bf[ni] = *(const bf16x8*)&Bls[wc * 64 + ni * 16 + frow][fkof];
#pragma unroll
        for (int mi = 0; mi < 4; ++mi)
#pragma unroll
            for (int ni = 0; ni < 4; ++ni)
                acc[mi][ni] = __builtin_amdgcn_mfma_f32_16x16x32_bf16(af[mi], bf[ni], acc[mi][ni], 0, 0, 0);
    }

    unsigned short* bdst = b0;
    int colbase = bn;
    bool act = false;
    if (MODE == 1) {
        const int seg = bn >> 10;
        bdst = (seg == 0) ? b0 : ((seg == 1) ? b1 : b2);
        colbase = bn & 1023;
        act = (seg < 2);
    }
    const int crow = (lane >> 4) << 2;
    const int ccol = lane & 15;
#pragma unroll
    for (int mi = 0; mi < 4; ++mi) {
#pragma unroll
        for (int ni = 0; ni < 4; ++ni) {
            const int col = colbase + wc * 64 + ni * 16 + ccol;
#pragma unroll
            for (int r = 0; r < 4; ++r) {
                const int row = bm + wr * 64 + mi * 16 + crow + r;
                float x = acc[mi][ni][r];
                if (MODE == 0) {
                    f32out[(size_t)row * 1024 + col] = x;
                } else {
                    if (act) x = (x > 0.f) ? (x + 1.f) : __expf(x);
                    bdst[(size_t)row * 1024 + col] = f2bf(x);
                }
            }
        }
    }
}

// ---------------------------------------------------------------------------
// rel: rel[m,h,s] = q[s]·norms[m,h];  relpart[(m*16+h)*4+seg] = partial sum
// grid (NMEM*NHEAD, 4), 256 threads; seg covers 512 s values.
// ---------------------------------------------------------------------------
__global__ __launch_bounds__(256) void rel_kernel(const unsigned short* __restrict__ qb,
                                                  const float* __restrict__ norms,
                                                  float* __restrict__ rel,
                                                  float* __restrict__ relpart) {
    const int m = blockIdx.x >> 4;
    const int h = blockIdx.x & 15;
    const int seg = blockIdx.y;
    __shared__ float nl[64];
    __shared__ float red[256];
    const int tid = threadIdx.x;
    if (tid < 64) nl[tid] = norms[(size_t)(m * NHEAD + h) * HD + tid];
    __syncthreads();
    float lsum = 0.f;
#pragma unroll
    for (int it = 0; it < 2; ++it) {
        const int s = seg * 512 + it * 256 + tid;
        const unsigned short* row = qb + (size_t)s * H_DIM + h * HD;
        float dot = 0.f;
#pragma unroll
        for (int d = 0; d < 64; d += 8) {
            u16x8 v = *(const u16x8*)(row + d);
#pragma unroll
            for (int i = 0; i < 8; ++i) dot += bf2f(v[i]) * nl[d + i];
        }
        rel[(size_t)(m * NHEAD + h) * S_LEN + s] = dot;
        lsum += dot;
    }
    red[tid] = lsum;
    __syncthreads();
    for (int o = 128; o > 0; o >>= 1) {
        if (tid < o) red[tid] += red[tid + o];
        __syncthreads();
    }
    if (tid == 0) relpart[(m * NHEAD + h) * 4 + seg] = red[0];
}

// ---------------------------------------------------------------------------
// chunkkv: per (h,c), MFMA  ckv[h,c][e][d] = sum_s v[s,e]*k[s,d]  (f32)
// and ksum via MFMA with all-ones A: cksc[h,c,d] = sum_s k[s,d].
// grid (NHEAD, NCHUNK), 256 threads.
// ---------------------------------------------------------------------------
__global__ __launch_bounds__(256) void chunkkv_kernel(const unsigned short* __restrict__ kb,
                                                      const unsigned short* __restrict__ vb,
                                                      float* __restrict__ ckv,
                                                      float* __restrict__ cksc) {
    const int h = blockIdx.x;
    const int c = blockIdx.y;
    const int s0 = c * CLEN;
    __shared__ unsigned short KT[4096], VT[4096];   // swizzled [d][s], [e][s]
    char* KTb = (char*)KT;
    char* VTb = (char*)VT;
    const int tid = threadIdx.x;
    const int lane = tid & 63;
    const int w = tid >> 6;
    const int fr = lane & 15;
    const int fk = (lane >> 4) * 8;
    const int er = w * 16 + (lane >> 4) * 4;

    const int idx0 = tid * 8, idx1 = 2048 + tid * 8;
    const int r0 = idx0 >> 6, c0 = idx0 & 63;
    const int r1 = idx1 >> 6, c1 = idx1 & 63;

    u16x8 k0 = *(const u16x8*)&kb[(size_t)(s0 + r0) * H_DIM + h * HD + c0];
    u16x8 k1 = *(const u16x8*)&kb[(size_t)(s0 + r1) * H_DIM + h * HD + c1];
    u16x8 v0 = *(const u16x8*)&vb[(size_t)(s0 + r0) * H_DIM + h * HD + c0];
    u16x8 v1 = *(const u16x8*)&vb[(size_t)(s0 + r1) * H_DIM + h * HD + c1];
#pragma unroll
    for (int j = 0; j < 8; ++j) {
        *(unsigned short*)(KTb + SWZ(c0 + j, r0 * 2)) = (unsigned short)k0[j];
        *(unsigned short*)(KTb + SWZ(c1 + j, r1 * 2)) = (unsigned short)k1[j];
        *(unsigned short*)(VTb + SWZ(c0 + j, r0 * 2)) = (unsigned short)v0[j];
        *(unsigned short*)(VTb + SWZ(c1 + j, r1 * 2)) = (unsigned short)v1[j];
    }
    __syncthreads();

    // V^T K: A = VT rows (e), B = KT rows (d)
    bf16x8 a0 = *(bf16x8*)(VTb + SWZ(w * 16 + fr, fk * 2));
    bf16x8 a1 = *(bf16x8*)(VTb + SWZ(w * 16 + fr, (32 + fk) * 2));
    f32x4 acc[4] = {};
    // ksum: all-ones A against this wave's own d-tile (B rows w*16+fr)
    bf16x8 ones;
#pragma unroll
    for (int i = 0; i < 8; ++i) ones[i] = (short)0x3F80;
    bf16x8 bw0 = *(bf16x8*)(KTb + SWZ(w * 16 + fr, fk * 2));
    bf16x8 bw1 = *(bf16x8*)(KTb + SWZ(w * 16 + fr, (32 + fk) * 2));
    f32x4 ka = {};
    ka = __builtin_amdgcn_mfma_f32_16x16x32_bf16(ones, bw0, ka, 0, 0, 0);
    ka = __builtin_amdgcn_mfma_f32_16x16x32_bf16(ones, bw1, ka, 0, 0, 0);
#pragma unroll
    for (int nt = 0; nt < 4; ++nt) {
        bf16x8 b0 = *(bf16x8*)(KTb + SWZ(nt * 16 + fr, fk * 2));
        bf16x8 b1 = *(bf16x8*)(KTb + SWZ(nt * 16 + fr, (32 + fk) * 2));
        acc[nt] = __builtin_amdgcn_mfma_f32_16x16x32_bf16(a0, b0, acc[nt], 0, 0, 0);
        acc[nt] = __builtin_amdgcn_mfma_f32_16x16x32_bf16(a1, b1, acc[nt], 0, 0, 0);
    }

    float* dst = ckv + ((size_t)(h * NCHUNK + c) << 12);
#pragma unroll
    for (int nt = 0; nt < 4; ++nt) {
        const int d = nt * 16 + fr;
#pragma unroll
        for (int r = 0; r < 4; ++r)
            dst[(er + r) * 64 + d] = acc[nt][r];
    }
    if (lane < 16)   // D rows identical; take reg 0 of the row-0 lane group
        cksc[(size_t)(h * NCHUNK + c) * HD + w * 16 + lane] = ka[0];
}

// ---------------------------------------------------------------------------
// prefix: exclusive scan over chunks. grid (NHEAD, 8), 256 threads.
// reads f32 ckv/cksc, writes bf16 ckvT_b + f32 cks.
// ---------------------------------------------------------------------------
__global__ __launch_bounds__(256) void prefix_kernel(const float* __restrict__ ckv,
                                                     const float* __restrict__ cksc,
                                                     unsigned short* __restrict__ ckvT_b,
                                                     float* __restrict__ cks) {
    const int h = blockIdx.x;
    const int g = blockIdx.y;
    const int tid = threadIdx.x;
    const int fo = g * 512 + tid * 2;
    const size_t base = ((size_t)(h * NCHUNK)) << 12;
    float rx = 0.f, ry = 0.f;
    float2 cur = *(const float2*)&ckv[base + fo];
    for (int c = 0; c < NCHUNK; ++c) {
        const size_t cb_ = base + ((size_t)c << 12) + fo;
        float2 nxt;
        if (c + 1 < NCHUNK) nxt = *(const float2*)&ckv[cb_ + 4096];
        else { nxt.x = 0.f; nxt.y = 0.f; }
        *(unsigned int*)&ckvT_b[cb_] =
            ((unsigned int)f2bf(ry) << 16) | (unsigned int)f2bf(rx);
        rx += cur.x; ry += cur.y;
        cur = nxt;
    }
    if (g == 0 && tid < 64) {
        float rk = 0.f;
        for (int c = 0; c < NCHUNK; ++c) {
            const size_t ci = (size_t)(h * NCHUNK + c) * HD + tid;
            cks[ci] = rk;
            rk += cksc[ci];
        }
    }
}

// ---------------------------------------------------------------------------
// Fused output kernel for one (head, chunk): memory retrieval + causal local
// attention, all MFMA; softmax memory weights computed inline from relpart.
// ---------------------------------------------------------------------------
__global__ __launch_bounds__(256) void fused_out_kernel(const unsigned short* __restrict__ qb,
                                                        const unsigned short* __restrict__ kb,
                                                        const unsigned short* __restrict__ vb,
                                                        const unsigned short* __restrict__ ckvT_b,
                                                        const float* __restrict__ cks,
                                                        const unsigned short* __restrict__ mbT,
                                                        const float* __restrict__ rel,
                                                        const float* __restrict__ relpart,
                                                        const float* __restrict__ gate,
                                                        unsigned short* __restrict__ cb) {
    const int h = blockIdx.x;
    const int c = blockIdx.y;
    const int s0 = c * CLEN;
    __shared__ unsigned short Qs[4096], Ks[4096], VsT[4096], KVsT[4096], Ps[4096];
    __shared__ unsigned short Ms[4][4096];
    __shared__ float kp_lds[64];
    __shared__ float den_lds[64];
    __shared__ float c_lds[4][64];
    char* Qb  = (char*)Qs;
    char* Kb  = (char*)Ks;
    char* Vb  = (char*)VsT;
    char* KVb = (char*)KVsT;
    char* Pb  = (char*)Ps;
    const int tid = threadIdx.x;
    const int lane = tid & 63;
    const int w = tid >> 6;

    // --- stage Q, K (row-major), V (transposed) ---
#pragma unroll
    for (int p = 0; p < 2; ++p) {
        const int idx = p * 2048 + tid * 8;
        const int r = idx >> 6, cc = idx & 63;
        const size_t gidx = (size_t)(s0 + r) * H_DIM + h * HD + cc;
        u16x8 q8 = *(const u16x8*)&qb[gidx];
        u16x8 k8 = *(const u16x8*)&kb[gidx];
        u16x8 v8 = *(const u16x8*)&vb[gidx];
        *(u16x8*)(Qb + SWZ(r, cc * 2)) = q8;
        *(u16x8*)(Kb + SWZ(r, cc * 2)) = k8;
#pragma unroll
        for (int j = 0; j < 8; ++j)
            *(unsigned short*)(Vb + SWZ(cc + j, r * 2)) = (unsigned short)v8[j];
    }
    // --- stage KVpre^T (bf16, already [e][d]) + memories ---
    const unsigned short* kvsrc = ckvT_b + ((size_t)(h * NCHUNK + c) << 12);
#pragma unroll
    for (int p = 0; p < 2; ++p) {
        const int idx = p * 2048 + tid * 8;
        const int e = idx >> 6, d = idx & 63;
        *(u16x8*)(KVb + SWZ(e, d * 2)) = *(const u16x8*)&kvsrc[idx];
    }
#pragma unroll
    for (int m = 0; m < NMEM; ++m) {
        const unsigned short* msrc = mbT + (size_t)(m * NHEAD + h) * 4096;
        char* Mb = (char*)Ms[m];
#pragma unroll
        for (int p = 0; p < 2; ++p) {
            const int idx = p * 2048 + tid * 8;
            const int e = idx >> 6, d = idx & 63;
            *(u16x8*)(Mb + SWZ(e, d * 2)) = *(const u16x8*)&msrc[idx];
        }
    }
    if (tid < 64) kp_lds[tid] = cks[(size_t)(h * NCHUNK + c) * HD + tid];
    {
        // inline softmax weights over memories (from 4-segment partials)
        const int m = tid >> 6, si = tid & 63;
        float v[NMEM], mx = -1e30f;
#pragma unroll
        for (int mm = 0; mm < NMEM; ++mm) {
            const float* rp = &relpart[(mm * NHEAD + h) * 4];
            v[mm] = (rp[0] + rp[1] + rp[2] + rp[3]) * (1.f / (float)S_LEN);
            mx = fmaxf(mx, v[mm]);
        }
        float sum = 0.f;
#pragma unroll
        for (int mm = 0; mm < NMEM; ++mm) { v[mm] = __expf(v[mm] - mx); sum += v[mm]; }
        const float wgt = v[m] / sum;
        c_lds[m][si] = wgt / fmaxf(rel[(size_t)(m * NHEAD + h) * S_LEN + s0 + si], EPS_C);
    }
    __syncthreads();

    // --- den_init[s] = q[s]·kpre ---
    {
        const int s = tid >> 2, part = tid & 3;
        float acc = 0.f;
#pragma unroll
        for (int j = 0; j < 16; ++j) {
            const int d = part * 16 + j;
            acc += bf2f(*(unsigned short*)(Qb + SWZ(s, d * 2))) * kp_lds[d];
        }
        acc += __shfl_xor(acc, 1);
        acc += __shfl_xor(acc, 2);
        if (part == 0) den_lds[s] = acc;
    }

    // --- QK^T ---
    const int sb = w * 16;
    const int fr = lane & 15;
    const int fk = (lane >> 4) * 8;
    bf16x8 aq0 = *(bf16x8*)(Qb + SWZ(sb + fr, fk * 2));
    bf16x8 aq1 = *(bf16x8*)(Qb + SWZ(sb + fr, (32 + fk) * 2));
    f32x4 aqk[4] = {};
#pragma unroll
    for (int nt = 0; nt < 4; ++nt) {
        bf16x8 bk0 = *(bf16x8*)(Kb + SWZ(nt * 16 + fr, fk * 2));
        bf16x8 bk1 = *(bf16x8*)(Kb + SWZ(nt * 16 + fr, (32 + fk) * 2));
        aqk[nt] = __builtin_amdgcn_mfma_f32_16x16x32_bf16(aq0, bk0, aqk[nt], 0, 0, 0);
        aqk[nt] = __builtin_amdgcn_mfma_f32_16x16x32_bf16(aq1, bk1, aqk[nt], 0, 0, 0);
    }
    // mask (t<=s), write P bf16, accumulate row sums
    float rs[4] = {0.f, 0.f, 0.f, 0.f};
    const int srow0 = sb + (lane >> 4) * 4;
#pragma unroll
    for (int nt = 0; nt < 4; ++nt) {
        const int t = nt * 16 + fr;
#pragma unroll
        for (int r = 0; r < 4; ++r) {
            const int s = srow0 + r;
            const float pv = (t <= s) ? aqk[nt][r] : 0.f;
            rs[r] += pv;
            *(unsigned short*)(Pb + SWZ(s, t * 2)) = f2bf(pv);
        }
    }
#pragma unroll
    for (int m = 1; m < 16; m <<= 1) {
        rs[0] += __shfl_xor(rs[0], m);
        rs[1] += __shfl_xor(rs[1], m);
        rs[2] += __shfl_xor(rs[2], m);
        rs[3] += __shfl_xor(rs[3], m);
    }
    if (fr == 0) {
#pragma unroll
        for (int r = 0; r < 4; ++r) den_lds[srow0 + r] += rs[r];
    }
    __syncthreads();

    // --- num = P@V + Q@KVpre; mem = sum_m c_m * (Q@M_m^T); epilogue ---
    const float g = 1.f / (1.f + __expf(-gate[h]));
    const float gl = 1.f - g;
#pragma unroll
    for (int nt = 0; nt < 4; ++nt) {
        const int br = nt * 16 + fr;
        f32x4 lacc = {};
        bf16x8 ap0 = *(bf16x8*)(Pb + SWZ(sb + fr, fk * 2));
        bf16x8 ap1 = *(bf16x8*)(Pb + SWZ(sb + fr, (32 + fk) * 2));
        bf16x8 bv0 = *(bf16x8*)(Vb + SWZ(br, fk * 2));
        bf16x8 bv1 = *(bf16x8*)(Vb + SWZ(br, (32 + fk) * 2));
        lacc = __builtin_amdgcn_mfma_f32_16x16x32_bf16(ap0, bv0, lacc, 0, 0, 0);
        lacc = __builtin_amdgcn_mfma_f32_16x16x32_bf16(ap1, bv1, lacc, 0, 0, 0);
        bf16x8 bkv0 = *(bf16x8*)(KVb + SWZ(br, fk * 2));
        bf16x8 bkv1 = *(bf16x8*)(KVb + SWZ(br, (32 + fk) * 2));
        lacc = __builtin_amdgcn_mfma_f32_16x16x32_bf16(aq0, bkv0, lacc, 0, 0, 0);
        lacc = __builtin_amdgcn_mfma_f32_16x16x32_bf16(aq1, bkv1, lacc, 0, 0, 0);

        f32x4 macc = {};
#pragma unroll
        for (int m = 0; m < NMEM; ++m) {
            char* Mb = (char*)Ms[m];
            bf16x8 bm0 = *(bf16x8*)(Mb + SWZ(br, fk * 2));
            bf16x8 bm1 = *(bf16x8*)(Mb + SWZ(br, (32 + fk) * 2));
            f32x4 mm = {};
            mm = __builtin_amdgcn_mfma_f32_16x16x32_bf16(aq0, bm0, mm, 0, 0, 0);
            mm = __builtin_amdgcn_mfma_f32_16x16x32_bf16(aq1, bm1, mm, 0, 0, 0);
#pragma unroll
            for (int r = 0; r < 4; ++r)
                macc[r] = fmaf(c_lds[m][srow0 + r], mm[r], macc[r]);
        }

        const int e = nt * 16 + fr;
#pragma unroll
        for (int r = 0; r < 4; ++r) {
            const int s = srow0 + r;
            const float den = fmaxf(den_lds[s], EPS_C);
            const float val = g * macc[r] + gl * lacc[r] / den;
            cb[(size_t)(s0 + s) * H_DIM + h * HD + e] = f2bf(val);
        }
    }
}

extern "C" void kernel_launch(void* const* d_in, const int* in_sizes, int n_in,
                              void* d_out, int out_size, void* d_ws, size_t ws_size,
                              hipStream_t stream) {
    const float* hidden   = (const float*)d_in[0];
    const float* w_q      = (const float*)d_in[1];
    const float* w_k      = (const float*)d_in[2];
    const float* w_v      = (const float*)d_in[3];
    const float* w_o      = (const float*)d_in[4];
    const float* gate     = (const float*)d_in[5];
    const float* memories = (const float*)d_in[6];
    const float* memnorms = (const float*)d_in[7];
    float* out = (float*)d_out;

    float* ws = (float*)d_ws;
    size_t off = 0;
    float* rel     = ws + off; off += (size_t)NMEM * NHEAD * S_LEN;
    float* relpart = ws + off; off += 256;
    float* cks     = ws + off; off += (size_t)NHEAD * NCHUNK * HD;
    float* cksc    = ws + off; off += (size_t)NHEAD * NCHUNK * HD;
    float* ckv     = ws + off; off += (size_t)NHEAD * NCHUNK * HD * HD;
    unsigned short* ckvT_b = (unsigned short*)(ws + off); off += (size_t)NHEAD * NCHUNK * HD * HD / 2;
    unsigned short* hb  = (unsigned short*)(ws + off); off += (size_t)S_LEN * H_DIM / 2;
    unsigned short* wb  = (unsigned short*)(ws + off); off += (size_t)3 * H_DIM * H_DIM / 2;
    unsigned short* wob = (unsigned short*)(ws + off); off += (size_t)H_DIM * H_DIM / 2;
    unsigned short* qb  = (unsigned short*)(ws + off); off += (size_t)S_LEN * H_DIM / 2;
    unsigned short* kb  = (unsigned short*)(ws + off); off += (size_t)S_LEN * H_DIM / 2;
    unsigned short* vb  = (unsigned short*)(ws + off); off += (size_t)S_LEN * H_DIM / 2;
    unsigned short* cb  = (unsigned short*)(ws + off); off += (size_t)S_LEN * H_DIM / 2;
    unsigned short* mbT = (unsigned short*)(ws + off); off += (size_t)NMEM * NHEAD * HD * HD / 2;

    // 1. all conversions + memory transpose
    prep_kernel<<<3136, 256, 0, stream>>>(hidden, w_q, w_k, w_v, w_o, memories,
                                          hb, wb, wob, mbT);
    // 2. fused QKV projection -> q/k/v bf16
    gemm_mfma_kernel<1><<<dim3(S_LEN / 128, 3 * H_DIM / 128), 256, 0, stream>>>(
        hb, wb, nullptr, qb, kb, vb, H_DIM);
    // 3. memory-selection relevance (4-way s-split)
    rel_kernel<<<dim3(NMEM * NHEAD, 4), 256, 0, stream>>>(qb, memnorms, rel, relpart);
    // 4. per-chunk KV state (MFMA, 512 blocks)
    chunkkv_kernel<<<dim3(NHEAD, NCHUNK), 256, 0, stream>>>(kb, vb, ckv, cksc);
    // 5. exclusive prefix scan (128 blocks)
    prefix_kernel<<<dim3(NHEAD, 8), 256, 0, stream>>>(ckv, cksc, ckvT_b, cks);
    // 6. fused memory + local output
    fused_out_kernel<<<dim3(NHEAD, NCHUNK), 256, 0, stream>>>(
        qb, kb, vb, ckvT_b, cks, mbT, rel, relpart, gate, cb);
    // 7. output projection
    gemm_mfma_kernel<0><<<dim3(S_LEN / 128, H_DIM / 128), 256, 0, stream>>>(
        cb, wob, out, nullptr, nullptr, nullptr, H_DIM);
}

// Round 7
// 86.173 us; speedup vs baseline: 1.6408x; 1.0885x over previous
//
#include <hip/hip_runtime.h>
#include <hip/hip_bf16.h>
#include <math.h>

#define S_LEN 2048
#define H_DIM 1024
#define NHEAD 16
#define HD 64
#define NMEM 4
#define NCHUNK 32
#define CLEN 64
#define EPS_C 1e-6f

typedef __attribute__((ext_vector_type(8))) short bf16x8;
typedef __attribute__((ext_vector_type(4))) float f32x4;
typedef __attribute__((ext_vector_type(8))) unsigned short u16x8;
typedef __attribute__((ext_vector_type(4))) unsigned short u16x4;

__device__ __forceinline__ unsigned short f2bf(float f) {
    unsigned int u = __float_as_uint(f);
    u += 0x7FFFu + ((u >> 16) & 1u);   // round-to-nearest-even
    return (unsigned short)(u >> 16);
}
__device__ __forceinline__ float bf2f(unsigned short u) {
    return __uint_as_float((unsigned int)u << 16);
}

// swizzle for 64x64 bf16 tiles, 128B rows (G4: byte ^= (row&7)<<4)
#define SWZ(row, colbyte) ((row) * 128 + ((colbyte) ^ (((row) & 7) << 4)))

// ---------------------------------------------------------------------------
// prep: all f32->bf16 conversions + memories transpose, one launch.
// ---------------------------------------------------------------------------
__global__ __launch_bounds__(256) void prep_kernel(const float* __restrict__ hidden,
                                                   const float* __restrict__ w_q,
                                                   const float* __restrict__ w_k,
                                                   const float* __restrict__ w_v,
                                                   const float* __restrict__ w_o,
                                                   const float* __restrict__ memories,
                                                   unsigned short* __restrict__ hb,
                                                   unsigned short* __restrict__ wb,
                                                   unsigned short* __restrict__ wob,
                                                   unsigned short* __restrict__ mbT) {
    const int b = blockIdx.x;
    const int tid = threadIdx.x;
    __shared__ float t[64][65];
    if (b < 3072) {
        const float* src;
        unsigned short* dst;
        int base;
        if (b < 1024)      { src = hidden; dst = hb;            base = b; }
        else if (b < 1536) { src = w_q;    dst = wb;            base = b - 1024; }
        else if (b < 2048) { src = w_k;    dst = wb + 1048576;  base = b - 1536; }
        else if (b < 2560) { src = w_v;    dst = wb + 2097152;  base = b - 2048; }
        else               { src = w_o;    dst = wob;           base = b - 2560; }
        const int i = base * 2048 + tid * 8;
        float4 a = *(const float4*)(src + i);
        float4 c = *(const float4*)(src + i + 4);
        u16x8 o;
        o[0] = f2bf(a.x); o[1] = f2bf(a.y); o[2] = f2bf(a.z); o[3] = f2bf(a.w);
        o[4] = f2bf(c.x); o[5] = f2bf(c.y); o[6] = f2bf(c.z); o[7] = f2bf(c.w);
        *(u16x8*)(dst + i) = o;
    } else {
        const int mh = b - 3072;
        const float* src = memories + (size_t)mh * 4096;
#pragma unroll
        for (int j = 0; j < 4; ++j) {
            const int idx = j * 1024 + tid * 4;
            *(float4*)&t[idx >> 6][idx & 63] = *(const float4*)&src[idx];
        }
        __syncthreads();
        unsigned short* dst = mbT + (size_t)mh * 4096;
#pragma unroll
        for (int j = 0; j < 4; ++j) {
            const int idx = j * 1024 + tid * 4;
            const int e = idx >> 6, d = idx & 63;
            u16x4 o;
#pragma unroll
            for (int i = 0; i < 4; ++i) o[i] = f2bf(t[d + i][e]);
            *(u16x4*)&dst[idx] = o;
        }
    }
}

// ---------------------------------------------------------------------------
// MFMA bf16 GEMM, BM=64 x BN=128 tiles (grid-balance: qkv 768 blk = 3/CU,
// out 256 blk = 1/CU). 1D grid with XCD-chunked remap (each XCD gets `perx`
// contiguous N-columns). 4 waves in 2x2: wave = 32 rows x 64 cols.
// MODE 0: f32 out (no act). MODE 1: qkv fused, bf16 out, elu1 on seg 0/1.
// ---------------------------------------------------------------------------
template <int MODE>
__global__ __launch_bounds__(256) void gemm_mfma_kernel(const unsigned short* __restrict__ A,
                                                        const unsigned short* __restrict__ B,
                                                        float* __restrict__ f32out,
                                                        unsigned short* __restrict__ b0,
                                                        unsigned short* __restrict__ b1,
                                                        unsigned short* __restrict__ b2,
                                                        int K, int perx) {
    __shared__ unsigned short Als[64][32];
    __shared__ unsigned short Bls[128][32];
    const int tid  = threadIdx.x;
    const int lane = tid & 63;
    const int wv   = tid >> 6;
    const int wr   = wv >> 1;           // row half (0..1) -> 32 rows
    const int wc   = wv & 1;            // col half (0..1) -> 64 cols
    // XCD-chunked remap: xcd = d&7 owns perx consecutive N-columns.
    const int d    = blockIdx.x;
    const int xcd  = d & 7;
    const int j    = d >> 3;
    const int y    = xcd * perx + (j >> 5);
    const int x    = j & 31;
    const int bm   = x * 64;
    const int bn   = y * 128;

    const int lrow = lane >> 2;                 // 0..15
    const int skc  = (lane & 3) << 3;
    const unsigned short* gA = A + (size_t)(bm + (wv << 4) + lrow) * K + skc;
    const unsigned short* gB = B + (size_t)(bn + (wv << 5) + lrow) * K + skc;

    const int frow = lane & 15;
    const int fkof = (lane >> 4) << 3;

    f32x4 acc[2][4] = {};

    for (int k0 = 0; k0 < K; k0 += 32) {
        __syncthreads();
        __builtin_amdgcn_global_load_lds(
            (const __attribute__((address_space(1))) void*)(gA + k0),
            (__attribute__((address_space(3))) void*)&Als[(wv << 4)][0], 16, 0, 0);
        __builtin_amdgcn_global_load_lds(
            (const __attribute__((address_space(1))) void*)(gB + k0),
            (__attribute__((address_space(3))) void*)&Bls[(wv << 5)][0], 16, 0, 0);
        __builtin_amdgcn_global_load_lds(
            (const __attribute__((address_space(1))) void*)(gB + k0 + 16 * (size_t)K),
            (__attribute__((address_space(3))) void*)&Bls[(wv << 5) + 16][0], 16, 0, 0);
        __syncthreads();

        bf16x8 af[2], bf[4];
#pragma unroll
        for (int mi = 0; mi < 2; ++mi)
            af[mi] = *(const bf16x8*)&Als[wr * 32 + mi * 16 + frow][fkof];
#pragma unroll
        for (int ni = 0; ni < 4; ++ni)
            bf[ni] = *(const bf16x8*)&Bls[wc * 64 + ni * 16 + frow][fkof];
#pragma unroll
        for (int mi = 0; mi < 2; ++mi)
#pragma unroll
            for (int ni = 0; ni < 4; ++ni)
                acc[mi][ni] = __builtin_amdgcn_mfma_f32_16x16x32_bf16(af[mi], bf[ni], acc[mi][ni], 0, 0, 0);
    }

    unsigned short* bdst = b0;
    int colbase = bn;
    bool act = false;
    if (MODE == 1) {
        const int seg = bn >> 10;
        bdst = (seg == 0) ? b0 : ((seg == 1) ? b1 : b2);
        colbase = bn & 1023;
        act = (seg < 2);
    }
    const int crow = (lane >> 4) << 2;
    const int ccol = lane & 15;
#pragma unroll
    for (int mi = 0; mi < 2; ++mi) {
#pragma unroll
        for (int ni = 0; ni < 4; ++ni) {
            const int col = colbase + wc * 64 + ni * 16 + ccol;
#pragma unroll
            for (int r = 0; r < 4; ++r) {
                const int row = bm + wr * 32 + mi * 16 + crow + r;
                float xv = acc[mi][ni][r];
                if (MODE == 0) {
                    f32out[(size_t)row * 1024 + col] = xv;
                } else {
                    if (act) xv = (xv > 0.f) ? (xv + 1.f) : __expf(xv);
                    bdst[(size_t)row * 1024 + col] = f2bf(xv);
                }
            }
        }
    }
}

// ---------------------------------------------------------------------------
// rel: one block per (h, seg of 512 s); reads q once, computes all 4 memories.
// rel[m,h,s] = q[s]·norms[m,h];  relpart[(m*16+h)*4+seg] = partial sum
// ---------------------------------------------------------------------------
__global__ __launch_bounds__(256) void rel_kernel(const unsigned short* __restrict__ qb,
                                                  const float* __restrict__ norms,
                                                  float* __restrict__ rel,
                                                  float* __restrict__ relpart) {
    const int h = blockIdx.x;
    const int seg = blockIdx.y;
    const int tid = threadIdx.x;
    __shared__ float nl[4][64];
    __shared__ float red[256];
    nl[tid >> 6][tid & 63] = norms[(size_t)((tid >> 6) * NHEAD + h) * HD + (tid & 63)];
    __syncthreads();
    float sums[4] = {0.f, 0.f, 0.f, 0.f};
#pragma unroll
    for (int it = 0; it < 2; ++it) {
        const int s = seg * 512 + it * 256 + tid;
        const unsigned short* row = qb + (size_t)s * H_DIM + h * HD;
        float dot[4] = {0.f, 0.f, 0.f, 0.f};
#pragma unroll
        for (int d0 = 0; d0 < 64; d0 += 8) {
            u16x8 v = *(const u16x8*)(row + d0);
#pragma unroll
            for (int i = 0; i < 8; ++i) {
                const float qv = bf2f(v[i]);
                dot[0] = fmaf(qv, nl[0][d0 + i], dot[0]);
                dot[1] = fmaf(qv, nl[1][d0 + i], dot[1]);
                dot[2] = fmaf(qv, nl[2][d0 + i], dot[2]);
                dot[3] = fmaf(qv, nl[3][d0 + i], dot[3]);
            }
        }
#pragma unroll
        for (int m = 0; m < NMEM; ++m) {
            rel[(size_t)(m * NHEAD + h) * S_LEN + s] = dot[m];
            sums[m] += dot[m];
        }
    }
#pragma unroll
    for (int m = 0; m < NMEM; ++m) {
        red[tid] = sums[m];
        __syncthreads();
        for (int o = 128; o > 0; o >>= 1) {
            if (tid < o) red[tid] += red[tid + o];
            __syncthreads();
        }
        if (tid == 0) relpart[(m * NHEAD + h) * 4 + seg] = red[0];
        __syncthreads();
    }
}

// ---------------------------------------------------------------------------
// chunkkv: per (h,c), MFMA  ckv_b[h,c][e][d] = bf16(sum_s v[s,e]*k[s,d])
// and ksum via MFMA with all-ones A: cksc[h,c,d] = sum_s k[s,d].
// ---------------------------------------------------------------------------
__global__ __launch_bounds__(256) void chunkkv_kernel(const unsigned short* __restrict__ kb,
                                                      const unsigned short* __restrict__ vb,
                                                      unsigned short* __restrict__ ckv_b,
                                                      float* __restrict__ cksc) {
    const int h = blockIdx.x;
    const int c = blockIdx.y;
    const int s0 = c * CLEN;
    __shared__ unsigned short KT[4096], VT[4096];   // swizzled [d][s], [e][s]
    char* KTb = (char*)KT;
    char* VTb = (char*)VT;
    const int tid = threadIdx.x;
    const int lane = tid & 63;
    const int w = tid >> 6;
    const int fr = lane & 15;
    const int fk = (lane >> 4) * 8;
    const int er = w * 16 + (lane >> 4) * 4;

    const int idx0 = tid * 8, idx1 = 2048 + tid * 8;
    const int r0 = idx0 >> 6, c0 = idx0 & 63;
    const int r1 = idx1 >> 6, c1 = idx1 & 63;

    u16x8 k0 = *(const u16x8*)&kb[(size_t)(s0 + r0) * H_DIM + h * HD + c0];
    u16x8 k1 = *(const u16x8*)&kb[(size_t)(s0 + r1) * H_DIM + h * HD + c1];
    u16x8 v0 = *(const u16x8*)&vb[(size_t)(s0 + r0) * H_DIM + h * HD + c0];
    u16x8 v1 = *(const u16x8*)&vb[(size_t)(s0 + r1) * H_DIM + h * HD + c1];
#pragma unroll
    for (int j = 0; j < 8; ++j) {
        *(unsigned short*)(KTb + SWZ(c0 + j, r0 * 2)) = (unsigned short)k0[j];
        *(unsigned short*)(KTb + SWZ(c1 + j, r1 * 2)) = (unsigned short)k1[j];
        *(unsigned short*)(VTb + SWZ(c0 + j, r0 * 2)) = (unsigned short)v0[j];
        *(unsigned short*)(VTb + SWZ(c1 + j, r1 * 2)) = (unsigned short)v1[j];
    }
    __syncthreads();

    bf16x8 a0 = *(bf16x8*)(VTb + SWZ(w * 16 + fr, fk * 2));
    bf16x8 a1 = *(bf16x8*)(VTb + SWZ(w * 16 + fr, (32 + fk) * 2));
    f32x4 acc[4] = {};
    bf16x8 ones;
#pragma unroll
    for (int i = 0; i < 8; ++i) ones[i] = (short)0x3F80;
    bf16x8 bw0 = *(bf16x8*)(KTb + SWZ(w * 16 + fr, fk * 2));
    bf16x8 bw1 = *(bf16x8*)(KTb + SWZ(w * 16 + fr, (32 + fk) * 2));
    f32x4 ka = {};
    ka = __builtin_amdgcn_mfma_f32_16x16x32_bf16(ones, bw0, ka, 0, 0, 0);
    ka = __builtin_amdgcn_mfma_f32_16x16x32_bf16(ones, bw1, ka, 0, 0, 0);
#pragma unroll
    for (int nt = 0; nt < 4; ++nt) {
        bf16x8 b0 = *(bf16x8*)(KTb + SWZ(nt * 16 + fr, fk * 2));
        bf16x8 b1 = *(bf16x8*)(KTb + SWZ(nt * 16 + fr, (32 + fk) * 2));
        acc[nt] = __builtin_amdgcn_mfma_f32_16x16x32_bf16(a0, b0, acc[nt], 0, 0, 0);
        acc[nt] = __builtin_amdgcn_mfma_f32_16x16x32_bf16(a1, b1, acc[nt], 0, 0, 0);
    }

    unsigned short* dst = ckv_b + ((size_t)(h * NCHUNK + c) << 12);
#pragma unroll
    for (int nt = 0; nt < 4; ++nt) {
        const int dd = nt * 16 + fr;
#pragma unroll
        for (int r = 0; r < 4; ++r)
            dst[(er + r) * 64 + dd] = f2bf(acc[nt][r]);
    }
    if (lane < 16)
        cksc[(size_t)(h * NCHUNK + c) * HD + w * 16 + lane] = ka[0];
}

// ---------------------------------------------------------------------------
// prefix: exclusive scan over chunks (bf16 in, f32 accumulate, bf16 out).
// grid (NHEAD, 8), 256 threads, 2 elems/thread.
// ---------------------------------------------------------------------------
__global__ __launch_bounds__(256) void prefix_kernel(const unsigned short* __restrict__ ckv_b,
                                                     const float* __restrict__ cksc,
                                                     unsigned short* __restrict__ ckvT_b,
                                                     float* __restrict__ cks) {
    const int h = blockIdx.x;
    const int g = blockIdx.y;
    const int tid = threadIdx.x;
    const int fo = g * 512 + tid * 2;
    const size_t base = ((size_t)(h * NCHUNK)) << 12;
    float rx = 0.f, ry = 0.f;
    unsigned int cur = *(const unsigned int*)&ckv_b[base + fo];
    for (int c = 0; c < NCHUNK; ++c) {
        const size_t cb_ = base + ((size_t)c << 12) + fo;
        unsigned int nxt = 0;
        if (c + 1 < NCHUNK) nxt = *(const unsigned int*)&ckv_b[cb_ + 4096];
        *(unsigned int*)&ckvT_b[cb_] =
            ((unsigned int)f2bf(ry) << 16) | (unsigned int)f2bf(rx);
        rx += bf2f((unsigned short)(cur & 0xFFFF));
        ry += bf2f((unsigned short)(cur >> 16));
        cur = nxt;
    }
    if (g == 0 && tid < 64) {
        float rk = 0.f;
        for (int c = 0; c < NCHUNK; ++c) {
            const size_t ci = (size_t)(h * NCHUNK + c) * HD + tid;
            cks[ci] = rk;
            rk += cksc[ci];
        }
    }
}

// ---------------------------------------------------------------------------
// Fused output kernel for one (head, chunk): memory retrieval + causal local
// attention, all MFMA; softmax memory weights computed inline from relpart.
// ---------------------------------------------------------------------------
__global__ __launch_bounds__(256) void fused_out_kernel(const unsigned short* __restrict__ qb,
                                                        const unsigned short* __restrict__ kb,
                                                        const unsigned short* __restrict__ vb,
                                                        const unsigned short* __restrict__ ckvT_b,
                                                        const float* __restrict__ cks,
                                                        const unsigned short* __restrict__ mbT,
                                                        const float* __restrict__ rel,
                                                        const float* __restrict__ relpart,
                                                        const float* __restrict__ gate,
                                                        unsigned short* __restrict__ cb) {
    const int h = blockIdx.x;
    const int c = blockIdx.y;
    const int s0 = c * CLEN;
    __shared__ unsigned short Qs[4096], Ks[4096], VsT[4096], KVsT[4096], Ps[4096];
    __shared__ unsigned short Ms[4][4096];
    __shared__ float kp_lds[64];
    __shared__ float den_lds[64];
    __shared__ float c_lds[4][64];
    char* Qb  = (char*)Qs;
    char* Kb  = (char*)Ks;
    char* Vb  = (char*)VsT;
    char* KVb = (char*)KVsT;
    char* Pb  = (char*)Ps;
    const int tid = threadIdx.x;
    const int lane = tid & 63;
    const int w = tid >> 6;

    // --- stage Q, K (row-major), V (transposed) ---
#pragma unroll
    for (int p = 0; p < 2; ++p) {
        const int idx = p * 2048 + tid * 8;
        const int r = idx >> 6, cc = idx & 63;
        const size_t gidx = (size_t)(s0 + r) * H_DIM + h * HD + cc;
        u16x8 q8 = *(const u16x8*)&qb[gidx];
        u16x8 k8 = *(const u16x8*)&kb[gidx];
        u16x8 v8 = *(const u16x8*)&vb[gidx];
        *(u16x8*)(Qb + SWZ(r, cc * 2)) = q8;
        *(u16x8*)(Kb + SWZ(r, cc * 2)) = k8;
#pragma unroll
        for (int j = 0; j < 8; ++j)
            *(unsigned short*)(Vb + SWZ(cc + j, r * 2)) = (unsigned short)v8[j];
    }
    // --- stage KVpre^T (bf16, already [e][d]) + memories ---
    const unsigned short* kvsrc = ckvT_b + ((size_t)(h * NCHUNK + c) << 12);
#pragma unroll
    for (int p = 0; p < 2; ++p) {
        const int idx = p * 2048 + tid * 8;
        const int e = idx >> 6, d = idx & 63;
        *(u16x8*)(KVb + SWZ(e, d * 2)) = *(const u16x8*)&kvsrc[idx];
    }
#pragma unroll
    for (int m = 0; m < NMEM; ++m) {
        const unsigned short* msrc = mbT + (size_t)(m * NHEAD + h) * 4096;
        char* Mb = (char*)Ms[m];
#pragma unroll
        for (int p = 0; p < 2; ++p) {
            const int idx = p * 2048 + tid * 8;
            const int e = idx >> 6, d = idx & 63;
            *(u16x8*)(Mb + SWZ(e, d * 2)) = *(const u16x8*)&msrc[idx];
        }
    }
    if (tid < 64) kp_lds[tid] = cks[(size_t)(h * NCHUNK + c) * HD + tid];
    {
        // inline softmax weights over memories (from 4-segment partials)
        const int m = tid >> 6, si = tid & 63;
        float v[NMEM], mx = -1e30f;
#pragma unroll
        for (int mm = 0; mm < NMEM; ++mm) {
            const float* rp = &relpart[(mm * NHEAD + h) * 4];
            v[mm] = (rp[0] + rp[1] + rp[2] + rp[3]) * (1.f / (float)S_LEN);
            mx = fmaxf(mx, v[mm]);
        }
        float sum = 0.f;
#pragma unroll
        for (int mm = 0; mm < NMEM; ++mm) { v[mm] = __expf(v[mm] - mx); sum += v[mm]; }
        const float wgt = v[m] / sum;
        c_lds[m][si] = wgt / fmaxf(rel[(size_t)(m * NHEAD + h) * S_LEN + s0 + si], EPS_C);
    }
    __syncthreads();

    // --- den_init[s] = q[s]·kpre ---
    {
        const int s = tid >> 2, part = tid & 3;
        float acc = 0.f;
#pragma unroll
        for (int j = 0; j < 16; ++j) {
            const int d = part * 16 + j;
            acc += bf2f(*(unsigned short*)(Qb + SWZ(s, d * 2))) * kp_lds[d];
        }
        acc += __shfl_xor(acc, 1);
        acc += __shfl_xor(acc, 2);
        if (part == 0) den_lds[s] = acc;
    }

    // --- QK^T ---
    const int sb = w * 16;
    const int fr = lane & 15;
    const int fk = (lane >> 4) * 8;
    bf16x8 aq0 = *(bf16x8*)(Qb + SWZ(sb + fr, fk * 2));
    bf16x8 aq1 = *(bf16x8*)(Qb + SWZ(sb + fr, (32 + fk) * 2));
    f32x4 aqk[4] = {};
#pragma unroll
    for (int nt = 0; nt < 4; ++nt) {
        bf16x8 bk0 = *(bf16x8*)(Kb + SWZ(nt * 16 + fr, fk * 2));
        bf16x8 bk1 = *(bf16x8*)(Kb + SWZ(nt * 16 + fr, (32 + fk) * 2));
        aqk[nt] = __builtin_amdgcn_mfma_f32_16x16x32_bf16(aq0, bk0, aqk[nt], 0, 0, 0);
        aqk[nt] = __builtin_amdgcn_mfma_f32_16x16x32_bf16(aq1, bk1, aqk[nt], 0, 0, 0);
    }
    // mask (t<=s), write P bf16, accumulate row sums
    float rs[4] = {0.f, 0.f, 0.f, 0.f};
    const int srow0 = sb + (lane >> 4) * 4;
#pragma unroll
    for (int nt = 0; nt < 4; ++nt) {
        const int t = nt * 16 + fr;
#pragma unroll
        for (int r = 0; r < 4; ++r) {
            const int s = srow0 + r;
            const float pv = (t <= s) ? aqk[nt][r] : 0.f;
            rs[r] += pv;
            *(unsigned short*)(Pb + SWZ(s, t * 2)) = f2bf(pv);
        }
    }
#pragma unroll
    for (int m = 1; m < 16; m <<= 1) {
        rs[0] += __shfl_xor(rs[0], m);
        rs[1] += __shfl_xor(rs[1], m);
        rs[2] += __shfl_xor(rs[2], m);
        rs[3] += __shfl_xor(rs[3], m);
    }
    if (fr == 0) {
#pragma unroll
        for (int r = 0; r < 4; ++r) den_lds[srow0 + r] += rs[r];
    }
    __syncthreads();

    // --- num = P@V + Q@KVpre; mem = sum_m c_m * (Q@M_m^T); epilogue ---
    const float g = 1.f / (1.f + __expf(-gate[h]));
    const float gl = 1.f - g;
#pragma unroll
    for (int nt = 0; nt < 4; ++nt) {
        const int br = nt * 16 + fr;
        f32x4 lacc = {};
        bf16x8 ap0 = *(bf16x8*)(Pb + SWZ(sb + fr, fk * 2));
        bf16x8 ap1 = *(bf16x8*)(Pb + SWZ(sb + fr, (32 + fk) * 2));
        bf16x8 bv0 = *(bf16x8*)(Vb + SWZ(br, fk * 2));
        bf16x8 bv1 = *(bf16x8*)(Vb + SWZ(br, (32 + fk) * 2));
        lacc = __builtin_amdgcn_mfma_f32_16x16x32_bf16(ap0, bv0, lacc, 0, 0, 0);
        lacc = __builtin_amdgcn_mfma_f32_16x16x32_bf16(ap1, bv1, lacc, 0, 0, 0);
        bf16x8 bkv0 = *(bf16x8*)(KVb + SWZ(br, fk * 2));
        bf16x8 bkv1 = *(bf16x8*)(KVb + SWZ(br, (32 + fk) * 2));
        lacc = __builtin_amdgcn_mfma_f32_16x16x32_bf16(aq0, bkv0, lacc, 0, 0, 0);
        lacc = __builtin_amdgcn_mfma_f32_16x16x32_bf16(aq1, bkv1, lacc, 0, 0, 0);

        f32x4 macc = {};
#pragma unroll
        for (int m = 0; m < NMEM; ++m) {
            char* Mb = (char*)Ms[m];
            bf16x8 bm0 = *(bf16x8*)(Mb + SWZ(br, fk * 2));
            bf16x8 bm1 = *(bf16x8*)(Mb + SWZ(br, (32 + fk) * 2));
            f32x4 mm = {};
            mm = __builtin_amdgcn_mfma_f32_16x16x32_bf16(aq0, bm0, mm, 0, 0, 0);
            mm = __builtin_amdgcn_mfma_f32_16x16x32_bf16(aq1, bm1, mm, 0, 0, 0);
#pragma unroll
            for (int r = 0; r < 4; ++r)
                macc[r] = fmaf(c_lds[m][srow0 + r], mm[r], macc[r]);
        }

        const int e = nt * 16 + fr;
#pragma unroll
        for (int r = 0; r < 4; ++r) {
            const int s = srow0 + r;
            const float den = fmaxf(den_lds[s], EPS_C);
            const float val = g * macc[r] + gl * lacc[r] / den;
            cb[(size_t)(s0 + s) * H_DIM + h * HD + e] = f2bf(val);
        }
    }
}

extern "C" void kernel_launch(void* const* d_in, const int* in_sizes, int n_in,
                              void* d_out, int out_size, void* d_ws, size_t ws_size,
                              hipStream_t stream) {
    const float* hidden   = (const float*)d_in[0];
    const float* w_q      = (const float*)d_in[1];
    const float* w_k      = (const float*)d_in[2];
    const float* w_v      = (const float*)d_in[3];
    const float* w_o      = (const float*)d_in[4];
    const float* gate     = (const float*)d_in[5];
    const float* memories = (const float*)d_in[6];
    const float* memnorms = (const float*)d_in[7];
    float* out = (float*)d_out;

    float* ws = (float*)d_ws;
    size_t off = 0;
    float* rel     = ws + off; off += (size_t)NMEM * NHEAD * S_LEN;
    float* relpart = ws + off; off += 256;
    float* cks     = ws + off; off += (size_t)NHEAD * NCHUNK * HD;
    float* cksc    = ws + off; off += (size_t)NHEAD * NCHUNK * HD;
    unsigned short* ckv_b  = (unsigned short*)(ws + off); off += (size_t)NHEAD * NCHUNK * HD * HD / 2;
    unsigned short* ckvT_b = (unsigned short*)(ws + off); off += (size_t)NHEAD * NCHUNK * HD * HD / 2;
    unsigned short* hb  = (unsigned short*)(ws + off); off += (size_t)S_LEN * H_DIM / 2;
    unsigned short* wb  = (unsigned short*)(ws + off); off += (size_t)3 * H_DIM * H_DIM / 2;
    unsigned short* wob = (unsigned short*)(ws + off); off += (size_t)H_DIM * H_DIM / 2;
    unsigned short* qb  = (unsigned short*)(ws + off); off += (size_t)S_LEN * H_DIM / 2;
    unsigned short* kb  = (unsigned short*)(ws + off); off += (size_t)S_LEN * H_DIM / 2;
    unsigned short* vb  = (unsigned short*)(ws + off); off += (size_t)S_LEN * H_DIM / 2;
    unsigned short* cb  = (unsigned short*)(ws + off); off += (size_t)S_LEN * H_DIM / 2;
    unsigned short* mbT = (unsigned short*)(ws + off); off += (size_t)NMEM * NHEAD * HD * HD / 2;

    // 1. all conversions + memory transpose
    prep_kernel<<<3136, 256, 0, stream>>>(hidden, w_q, w_k, w_v, w_o, memories,
                                          hb, wb, wob, mbT);
    // 2. fused QKV projection -> q/k/v bf16 (768 blocks = 3/CU, XCD-chunked)
    gemm_mfma_kernel<1><<<768, 256, 0, stream>>>(
        hb, wb, nullptr, qb, kb, vb, H_DIM, 3);
    // 3. memory-selection relevance (reads q once for all 4 memories)
    rel_kernel<<<dim3(NHEAD, 4), 256, 0, stream>>>(qb, memnorms, rel, relpart);
    // 4. per-chunk KV state (MFMA, 512 blocks, bf16 out)
    chunkkv_kernel<<<dim3(NHEAD, NCHUNK), 256, 0, stream>>>(kb, vb, ckv_b, cksc);
    // 5. exclusive prefix scan (128 blocks)
    prefix_kernel<<<dim3(NHEAD, 8), 256, 0, stream>>>(ckv_b, cksc, ckvT_b, cks);
    // 6. fused memory + local output
    fused_out_kernel<<<dim3(NHEAD, NCHUNK), 256, 0, stream>>>(
        qb, kb, vb, ckvT_b, cks, mbT, rel, relpart, gate, cb);
    // 7. output projection (256 blocks = 1/CU, XCD-chunked)
    gemm_mfma_kernel<0><<<256, 256, 0, stream>>>(
        cb, wob, out, nullptr, nullptr, nullptr, H_DIM, 1);
}